// Round 2
// baseline (241.307 us; speedup 1.0000x reference)
//
#include <hip/hip_runtime.h>

// SpectralConv3d — algebra (verified by previous passing runs):
//   fftn axes (2,3,4) = (D2, D3, CIN); D1 only sliced to <8 (output zero for d1>=8)
//   einsum sums i,j of w  => Weff[c,o,f3] = sum_ij w[c,o,i,j,f3]
//   DFT_c + mix + IDFT_c folds to fixed map T[c][f3][co]
//   ifftn norm 1/(64*64*32) = 1/131072
//
// Pipeline (4 kernels):
//   k_weff  -> Weff                     (tiny)
//   k_T     -> T                        (tiny)
//   k_mid2  : per (b,d1,f2) slab: d2-DFT from x (fused, no S1), d3-DFT,
//             T-mix, d3-IDFT -> S6.  Grid mapped f2-major so the 8 wgs
//             sharing an x slab land on the same XCD (L2 reuse).
//   k_final2: per (b,d1,d3blk): stage S6 slice in LDS once, d2-IDFT,
//             nontemporal stores; zero region (d1>=8) pure NT fill.

#define PI2F 6.28318530717958647692f

typedef float vf4 __attribute__((ext_vector_type(4)));  // native vec for NT stores

__device__ __forceinline__ float2 cmul(float2 a, float2 b) {
    return make_float2(a.x * b.x - a.y * b.y, a.x * b.y + a.y * b.x);
}

// Weff[fc][o][f3] = sum_{ij} (wr + i wi)[fc][o][i][j][f3]
__global__ void k_weff(const float* __restrict__ wr, const float* __restrict__ wi,
                       float2* __restrict__ Weff) {
    int t = blockIdx.x * 256 + threadIdx.x;   // 8192
    int base = (t >> 3) * 512 + (t & 7);      // (fc*32+o)*512 + f3; ij stride 8
    float sr = 0.f, si = 0.f;
    #pragma unroll 8
    for (int ij = 0; ij < 64; ++ij) { sr += wr[base + ij * 8]; si += wi[base + ij * 8]; }
    Weff[t] = make_float2(sr, si);
}

// T[c][f3][co] = sum_{fc,o} e^{-2pi i fc c/32} Weff[fc][o][f3] e^{+2pi i o co/32}
__global__ void k_T(const float2* __restrict__ Weff, float2* __restrict__ T) {
    __shared__ float2 tw32[32];
    __shared__ float2 A[256];
    int t = threadIdx.x;
    int c = blockIdx.x;
    if (t < 32) {
        float s, co_;
        __sincosf((PI2F / 32.f) * (float)t, &s, &co_);
        tw32[t] = make_float2(co_, s);
    }
    __syncthreads();
    {
        float2 acc = make_float2(0.f, 0.f);
        for (int fc = 0; fc < 32; ++fc) {
            float2 v = Weff[fc * 256 + t];        // t = o*8+f3
            float2 e = tw32[(fc * c) & 31];       // E^-
            acc.x += v.x * e.x + v.y * e.y;
            acc.y += v.y * e.x - v.x * e.y;
        }
        A[t] = acc;
    }
    __syncthreads();
    {
        int f3 = t >> 5, co = t & 31;
        float2 acc = make_float2(0.f, 0.f);
        for (int o = 0; o < 32; ++o) {
            float2 v = A[o * 8 + f3];
            float2 e = tw32[(o * co) & 31];       // E^+
            acc.x += v.x * e.x - v.y * e.y;
            acc.y += v.x * e.y + v.y * e.x;
        }
        T[c * 256 + t] = acc;                     // layout [c][f3][co]
    }
}

// Fused middle: gid = f2*32 + (b*8+d1)  (256 wgs)
//   stage0: lin[d3][c] = sum_d2 x[b][d1][d2][d3][c] E64^-(f2 d2)   (from global x)
//   stageA: ls2[f3][c] = sum_d3 lin * E64^-(f3 d3)
//   stageB: ls5[f3][co] = sum_c ls2 * T[c][f3][co]
//   stageC: S6[(b,d1,f2)][d3][co] = sum_f3 ls5 * E64^+(f3 d3)
__global__ void k_mid2(const float* __restrict__ x, const float2* __restrict__ T,
                       float2* __restrict__ S6) {
    __shared__ float2 lin[2048];    // [d3=64][c=32]
    __shared__ float2 ls2[256];     // [f3][c]
    __shared__ float2 ls5[256];     // [f3][co]
    __shared__ float2 tw64[64];
    int t = threadIdx.x;
    int gid = blockIdx.x;
    int f2 = gid >> 5;
    int s  = gid & 31;              // b*8 + d1
    int b  = s >> 3, d1 = s & 7;
    if (t < 64) {
        float sn, cs;
        __sincosf((PI2F / 64.f) * (float)t, &sn, &cs);
        tw64[t] = make_float2(cs, sn);
    }
    // stage 0: d2-DFT straight from x (each thread: 4 channels x 2 d3 rows)
    {
        int c4 = t & 7;
        int d3a = t >> 3;           // 0..31 ; second row d3a+32
        const float4* pa = (const float4*)(x + (size_t)b * 8388608 + (size_t)d1 * 131072
                                             + d3a * 32 + c4 * 4);
        const float4* pb = pa + 256;            // +32 d3 rows = 1024 floats
        float sn, cs;
        __sincosf((PI2F / 64.f) * (float)f2, &sn, &cs);
        float2 step = make_float2(cs, -sn);     // e^{-2pi i f2/64}
        float2 w = make_float2(1.f, 0.f);
        float2 accA0 = {0,0}, accA1 = {0,0}, accA2 = {0,0}, accA3 = {0,0};
        float2 accB0 = {0,0}, accB1 = {0,0}, accB2 = {0,0}, accB3 = {0,0};
        #pragma unroll 4
        for (int d2 = 0; d2 < 64; ++d2) {
            float4 va = pa[d2 * 512];           // 2048-float d2 stride
            float4 vb = pb[d2 * 512];
            accA0.x += va.x * w.x; accA0.y += va.x * w.y;
            accA1.x += va.y * w.x; accA1.y += va.y * w.y;
            accA2.x += va.z * w.x; accA2.y += va.z * w.y;
            accA3.x += va.w * w.x; accA3.y += va.w * w.y;
            accB0.x += vb.x * w.x; accB0.y += vb.x * w.y;
            accB1.x += vb.y * w.x; accB1.y += vb.y * w.y;
            accB2.x += vb.z * w.x; accB2.y += vb.z * w.y;
            accB3.x += vb.w * w.x; accB3.y += vb.w * w.y;
            w = cmul(w, step);
        }
        float2* la = lin + d3a * 32 + c4 * 4;
        float2* lb = la + 1024;                 // (d3a+32)*32
        la[0] = accA0; la[1] = accA1; la[2] = accA2; la[3] = accA3;
        lb[0] = accB0; lb[1] = accB1; lb[2] = accB2; lb[3] = accB3;
    }
    __syncthreads();
    // stage A: d3-DFT
    {
        int f3 = t >> 5, c = t & 31;
        float2 e = tw64[f3];
        float2 step = make_float2(e.x, -e.y);   // e^{-2pi i f3/64}
        float2 w = make_float2(1.f, 0.f);
        float2 acc = make_float2(0.f, 0.f);
        for (int d3 = 0; d3 < 64; ++d3) {
            float2 v = lin[d3 * 32 + c];
            acc.x += v.x * w.x - v.y * w.y;
            acc.y += v.x * w.y + v.y * w.x;
            w = cmul(w, step);
        }
        ls2[f3 * 32 + c] = acc;
    }
    __syncthreads();
    // stage B: channel map via T  (T layout [c][f3][co], t = f3*32+co)
    {
        int f3 = t >> 5;
        float2 acc = make_float2(0.f, 0.f);
        for (int c = 0; c < 32; ++c) {
            float2 a = ls2[f3 * 32 + c];
            float2 w = T[c * 256 + t];
            acc.x += a.x * w.x - a.y * w.y;
            acc.y += a.x * w.y + a.y * w.x;
        }
        ls5[t] = acc;
    }
    __syncthreads();
    // stage C: d3-IDFT -> S6
    {
        int co = t & 31, d3r = t >> 5;
        float2* outp = S6 + (size_t)(s * 8 + f2) * 2048;
        #pragma unroll
        for (int j = 0; j < 8; ++j) {
            int d3 = d3r + 8 * j;
            float2 acc = make_float2(0.f, 0.f);
            #pragma unroll
            for (int f3 = 0; f3 < 8; ++f3) {
                float2 v = ls5[f3 * 32 + co];
                float2 e = tw64[(f3 * d3) & 63];   // E^+
                acc.x += v.x * e.x - v.y * e.y;
                acc.y += v.x * e.y + v.y * e.x;
            }
            outp[d3 * 32 + co] = acc;
        }
    }
}

// k_final2: gid = (b*64 + d1)*8 + d3blk   (2048 wgs)
//   d1>=8: pure nontemporal zero fill.
//   d1< 8: stage S6[(b,d1)][f2 0..7][d3blk*8..+7][co 0..31] in LDS (16 KB),
//          hold the 8f2 x 4co fragment in regs, d2-IDFT with LDS twiddle
//          table, nontemporal float4 stores.
__global__ void k_final2(const float2* __restrict__ S6, float* __restrict__ out) {
    __shared__ float2 ls[2048];     // [f2=8][d3r=8][co=32]
    __shared__ float2 tw[64];
    int t = threadIdx.x;
    int gid = blockIdx.x;
    int blk = gid & 7;
    int d1  = (gid >> 3) & 63;
    int b   = gid >> 9;
    int co4 = t & 7;
    int d3r = (t >> 3) & 7;
    int d2q = t >> 6;               // wave-uniform
    float* obase = out + (size_t)b * 8388608 + (size_t)d1 * 131072
                 + (blk * 8 + d3r) * 32 + co4 * 4;
    if (d1 >= 8) {
        vf4 z = {0.f, 0.f, 0.f, 0.f};
        #pragma unroll
        for (int i = 0; i < 16; ++i) {
            int d2 = d2q * 16 + i;
            __builtin_nontemporal_store(z, (vf4*)(obase + d2 * 2048));
        }
        return;
    }
    if (t < 64) {
        float sn, cs;
        __sincosf((PI2F / 64.f) * (float)t, &sn, &cs);
        tw[t] = make_float2(cs, sn);            // E^+
    }
    // stage S6 slice: 1024 float4, coalesced (8 chunks of 2 KB)
    {
        const float4* src = (const float4*)(S6 + (size_t)(b * 8 + d1) * 16384);
        float4* dst = (float4*)ls;
        #pragma unroll
        for (int j = 0; j < 4; ++j) {
            int i4 = t + j * 256;               // 0..1023
            int f2 = i4 >> 7, rem = i4 & 127;
            dst[i4] = src[f2 * 1024 + blk * 128 + rem];
        }
    }
    __syncthreads();
    // fragment to registers: 8 f2 x 4 co (compile-time indexed)
    float2 v[8][4];
    #pragma unroll
    for (int f2 = 0; f2 < 8; ++f2) {
        #pragma unroll
        for (int k = 0; k < 4; ++k)
            v[f2][k] = ls[f2 * 256 + d3r * 32 + co4 * 4 + k];
    }
    const float sc = 1.f / 131072.f;
    #pragma unroll 2
    for (int i = 0; i < 16; ++i) {
        int d2 = d2q * 16 + i;
        float rx = 0.f, ry = 0.f, rz = 0.f, rw = 0.f;
        #pragma unroll
        for (int f2 = 0; f2 < 8; ++f2) {
            float2 e = tw[(f2 * d2) & 63];      // wave-uniform broadcast
            rx += v[f2][0].x * e.x - v[f2][0].y * e.y;
            ry += v[f2][1].x * e.x - v[f2][1].y * e.y;
            rz += v[f2][2].x * e.x - v[f2][2].y * e.y;
            rw += v[f2][3].x * e.x - v[f2][3].y * e.y;
        }
        vf4 r = {rx * sc, ry * sc, rz * sc, rw * sc};
        __builtin_nontemporal_store(r, (vf4*)(obase + d2 * 2048));
    }
}

extern "C" void kernel_launch(void* const* d_in, const int* in_sizes, int n_in,
                              void* d_out, int out_size, void* d_ws, size_t ws_size,
                              hipStream_t stream) {
    const float* x  = (const float*)d_in[0];
    const float* wr = (const float*)d_in[1];
    const float* wi = (const float*)d_in[2];
    float* out = (float*)d_out;

    float2* Weff = (float2*)d_ws;            // 8192 float2
    float2* T    = Weff + 8192;              // 8192 float2
    float2* S6   = T + 8192;                 // 524288 float2 (4 MiB)

    k_weff  <<<32,   256, 0, stream>>>(wr, wi, Weff);
    k_T     <<<32,   256, 0, stream>>>(Weff, T);
    k_mid2  <<<256,  256, 0, stream>>>(x, T, S6);
    k_final2<<<2048, 256, 0, stream>>>(S6, out);
}

// Round 3
// 222.892 us; speedup vs baseline: 1.0826x; 1.0826x over previous
//
#include <hip/hip_runtime.h>

// SpectralConv3d — algebra (verified by passing runs):
//   fftn axes (2,3,4) = (D2, D3, CIN); output zero for d1>=8
//   Weff[c,o,f3] = sum_ij w[c,o,i,j,f3];  DFT_c+mix+IDFT_c folds to T[c][f3][co]
//   ifftn norm 1/131072
//
// Round-3 rationale: round-2 was latency-bound (1 wave/SIMD in the mid path,
// 128 serial strided loads/thread). Reshape for occupancy:
//   k_weff : 256 wgs, ij-sum split 8-way + LDS reduce
//   k_T    : 32 wgs x 1024 thr, fc-/o-sums split 4-way + LDS reduce
//   k_dft2 : 2048 wgs (slab,d3): d2-DFT, x read EXACTLY once, 8 loads/thread
//   k_mid3 : 256 wgs x 1024 thr (slab,f2): d3-DFT + T-mix + d3-IDFT -> S6
//   k_final2: 2048 wgs: LDS-stage S6 slice, d2-IDFT, nontemporal stores

#define PI2F 6.28318530717958647692f

typedef float vf4 __attribute__((ext_vector_type(4)));  // native vec for NT stores

__device__ __forceinline__ float2 cmul(float2 a, float2 b) {
    return make_float2(a.x * b.x - a.y * b.y, a.x * b.y + a.y * b.x);
}

// Weff[fc][o][f3] = sum_{ij} (wr + i wi)[fc][o][i][j][f3]
// 256 wgs x 256 thr: wg owns 32 elems, ij split 8-way across thread groups.
__global__ void k_weff(const float* __restrict__ wr, const float* __restrict__ wi,
                       float2* __restrict__ Weff) {
    __shared__ float2 ls[256];
    int t = threadIdx.x;
    int eL = t & 31, ijg = t >> 5;
    int e = blockIdx.x * 32 + eL;                 // e = (fc*32+o)*8 + f3
    int base = (e >> 3) * 512 + (e & 7) + ijg * 64;   // ij stride 8 floats
    float sr = 0.f, si = 0.f;
    #pragma unroll
    for (int j = 0; j < 8; ++j) { sr += wr[base + j * 8]; si += wi[base + j * 8]; }
    ls[t] = make_float2(sr, si);
    __syncthreads();
    if (t < 32) {
        float2 a = ls[t];
        #pragma unroll
        for (int g = 1; g < 8; ++g) { float2 v = ls[g * 32 + t]; a.x += v.x; a.y += v.y; }
        Weff[blockIdx.x * 32 + t] = a;
    }
}

// T[c][f3][co] = sum_{fc,o} E32^-(fc c) Weff[fc][o][f3] E32^+(o co)
// 32 wgs (c) x 1024 thr; both 32-sums split 4-way.
__global__ void k_T(const float2* __restrict__ Weff, float2* __restrict__ T) {
    __shared__ float2 tw32[32];
    __shared__ float2 P[1024];
    __shared__ float2 A[256];
    int t = threadIdx.x;
    int c = blockIdx.x;
    if (t < 32) {
        float s, co_;
        __sincosf((PI2F / 32.f) * (float)t, &s, &co_);
        tw32[t] = make_float2(co_, s);
    }
    __syncthreads();
    {   // stage 1 partial: A[o][f3] = sum_fc Weff[fc][o*8+f3] * conj(tw32[fc*c])
        int g = t >> 8, rem = t & 255;            // rem = o*8+f3
        float2 acc = make_float2(0.f, 0.f);
        #pragma unroll
        for (int k = 0; k < 8; ++k) {
            int fc = g * 8 + k;
            float2 v = Weff[fc * 256 + rem];
            float2 e = tw32[(fc * c) & 31];
            acc.x += v.x * e.x + v.y * e.y;
            acc.y += v.y * e.x - v.x * e.y;
        }
        P[t] = acc;
    }
    __syncthreads();
    if (t < 256) {
        float2 a = P[t];
        #pragma unroll
        for (int g = 1; g < 4; ++g) { float2 v = P[g * 256 + t]; a.x += v.x; a.y += v.y; }
        A[t] = a;
    }
    __syncthreads();
    {   // stage 2 partial: T[c][f3][co] = sum_o A[o*8+f3] * tw32[o*co]
        int g = t >> 8, rem = t & 255;
        int f3 = rem >> 5, co = rem & 31;
        float2 acc = make_float2(0.f, 0.f);
        #pragma unroll
        for (int k = 0; k < 8; ++k) {
            int o = g * 8 + k;
            float2 v = A[o * 8 + f3];
            float2 e = tw32[(o * co) & 31];
            acc.x += v.x * e.x - v.y * e.y;
            acc.y += v.x * e.y + v.y * e.x;
        }
        P[t] = acc;
    }
    __syncthreads();
    if (t < 256) {
        float2 a = P[t];
        #pragma unroll
        for (int g = 1; g < 4; ++g) { float2 v = P[g * 256 + t]; a.x += v.x; a.y += v.y; }
        T[c * 256 + t] = a;
    }
}

// d2-DFT: S1[s][f2][d3][c] = sum_d2 x[b][d1][d2][d3][c] E64^-(f2 d2)
// 2048 wgs = (s=32) x (d3=64); 256 thr = (d2g=8) x (c=32); x read exactly once.
__global__ void k_dft2(const float* __restrict__ x, float2* __restrict__ S1) {
    __shared__ float2 tw64[64];
    __shared__ float2 P[2048];                    // [d2g*8+f2][c]  16 KB
    int t = threadIdx.x;
    int gid = blockIdx.x;
    int d3 = gid & 63, s = gid >> 6;
    int b = s >> 3, d1 = s & 7;
    int c = t & 31, d2g = t >> 5;
    if (t < 64) {
        float sn, cs;
        __sincosf((PI2F / 64.f) * (float)t, &sn, &cs);
        tw64[t] = make_float2(cs, sn);
    }
    __syncthreads();
    const float* xp = x + (size_t)b * 8388608 + (size_t)d1 * 131072 + d3 * 32 + c;
    float2 acc[8];
    #pragma unroll
    for (int f2 = 0; f2 < 8; ++f2) acc[f2] = make_float2(0.f, 0.f);
    #pragma unroll
    for (int k = 0; k < 8; ++k) {
        int d2 = d2g * 8 + k;
        float v = xp[d2 * 2048];
        #pragma unroll
        for (int f2 = 0; f2 < 8; ++f2) {
            float2 e = tw64[(f2 * d2) & 63];      // E^-: (cos, -sin) applied below
            acc[f2].x += v * e.x;
            acc[f2].y -= v * e.y;
        }
    }
    #pragma unroll
    for (int f2 = 0; f2 < 8; ++f2) P[(d2g * 8 + f2) * 32 + c] = acc[f2];
    __syncthreads();
    {
        int f2 = t >> 5, cc = t & 31;
        float2 a = make_float2(0.f, 0.f);
        #pragma unroll
        for (int g = 0; g < 8; ++g) {
            float2 v = P[(g * 8 + f2) * 32 + cc];
            a.x += v.x; a.y += v.y;
        }
        S1[(size_t)(s * 8 + f2) * 2048 + d3 * 32 + cc] = a;
    }
}

// Mid: 256 wgs = (s,f2) x 1024 thr.
//   A: s2[f3][c]  = sum_d3 S1slab[d3][c] E64^-(f3 d3)   (split 4-way over d3)
//   B: s5[f3][co] = sum_c  s2 * T[c][f3][co]            (split 4-way over c)
//   C: S6[d3][co] = sum_f3 s5 * E64^+(f3 d3)
__global__ void k_mid3(const float2* __restrict__ S1, const float2* __restrict__ T,
                       float2* __restrict__ S6) {
    __shared__ float2 sl1[2048];   // [d3][c] 16 KB
    __shared__ float2 P[1024];     // partials 8 KB (reused A/B)
    __shared__ float2 s2[256];
    __shared__ float2 s5[256];
    __shared__ float2 tw[64];
    int t = threadIdx.x;
    int gid = blockIdx.x;          // = s*8 + f2
    if (t < 64) {
        float sn, cs;
        __sincosf((PI2F / 64.f) * (float)t, &sn, &cs);
        tw[t] = make_float2(cs, sn);
    }
    {   // stage in slab (1024 x float4)
        const float4* src = (const float4*)(S1 + (size_t)gid * 2048);
        ((float4*)sl1)[t] = src[t];
    }
    __syncthreads();
    {   // A partial
        int g = t >> 8, rem = t & 255;
        int f3 = rem >> 5, c = rem & 31;
        float2 a = make_float2(0.f, 0.f);
        #pragma unroll 4
        for (int k = 0; k < 16; ++k) {
            int d3 = g * 16 + k;
            float2 v = sl1[d3 * 32 + c];
            float2 e = tw[(f3 * d3) & 63];        // conj applied
            a.x += v.x * e.x + v.y * e.y;
            a.y += v.y * e.x - v.x * e.y;
        }
        P[t] = a;
    }
    __syncthreads();
    if (t < 256) {
        float2 a = P[t];
        #pragma unroll
        for (int g = 1; g < 4; ++g) { float2 v = P[g * 256 + t]; a.x += v.x; a.y += v.y; }
        s2[t] = a;
    }
    __syncthreads();
    {   // B partial
        int g = t >> 8, rem = t & 255;
        int f3 = rem >> 5, co = rem & 31;
        float2 a = make_float2(0.f, 0.f);
        #pragma unroll
        for (int k = 0; k < 8; ++k) {
            int cc = g * 8 + k;
            float2 v = s2[f3 * 32 + cc];
            float2 w = T[cc * 256 + f3 * 32 + co];
            a.x += v.x * w.x - v.y * w.y;
            a.y += v.x * w.y + v.y * w.x;
        }
        P[t] = a;
    }
    __syncthreads();
    if (t < 256) {
        float2 a = P[t];
        #pragma unroll
        for (int g = 1; g < 4; ++g) { float2 v = P[g * 256 + t]; a.x += v.x; a.y += v.y; }
        s5[t] = a;
    }
    __syncthreads();
    {   // C: d3-IDFT -> S6, 2 outputs per thread
        int co = t & 31, d3a = t >> 5;            // 0..31
        float2* outp = S6 + (size_t)gid * 2048;
        #pragma unroll
        for (int h = 0; h < 2; ++h) {
            int d3 = d3a + 32 * h;
            float2 a = make_float2(0.f, 0.f);
            #pragma unroll
            for (int f3 = 0; f3 < 8; ++f3) {
                float2 v = s5[f3 * 32 + co];
                float2 e = tw[(f3 * d3) & 63];    // E^+
                a.x += v.x * e.x - v.y * e.y;
                a.y += v.x * e.y + v.y * e.x;
            }
            outp[d3 * 32 + co] = a;
        }
    }
}

// k_final2: gid = (b*64 + d1)*8 + d3blk   (2048 wgs)
//   d1>=8: pure nontemporal zero fill.
//   d1< 8: stage S6 slice in LDS (16 KB), regs fragment, d2-IDFT, NT stores.
__global__ void k_final2(const float2* __restrict__ S6, float* __restrict__ out) {
    __shared__ float2 ls[2048];     // [f2=8][d3r=8][co=32]
    __shared__ float2 tw[64];
    int t = threadIdx.x;
    int gid = blockIdx.x;
    int blk = gid & 7;
    int d1  = (gid >> 3) & 63;
    int b   = gid >> 9;
    int co4 = t & 7;
    int d3r = (t >> 3) & 7;
    int d2q = t >> 6;               // wave-uniform
    float* obase = out + (size_t)b * 8388608 + (size_t)d1 * 131072
                 + (blk * 8 + d3r) * 32 + co4 * 4;
    if (d1 >= 8) {
        vf4 z = {0.f, 0.f, 0.f, 0.f};
        #pragma unroll
        for (int i = 0; i < 16; ++i) {
            int d2 = d2q * 16 + i;
            __builtin_nontemporal_store(z, (vf4*)(obase + d2 * 2048));
        }
        return;
    }
    if (t < 64) {
        float sn, cs;
        __sincosf((PI2F / 64.f) * (float)t, &sn, &cs);
        tw[t] = make_float2(cs, sn);            // E^+
    }
    {   // stage S6 slice: 1024 float4
        const float4* src = (const float4*)(S6 + (size_t)(b * 8 + d1) * 16384);
        float4* dst = (float4*)ls;
        #pragma unroll
        for (int j = 0; j < 4; ++j) {
            int i4 = t + j * 256;               // 0..1023
            int f2 = i4 >> 7, rem = i4 & 127;
            dst[i4] = src[f2 * 1024 + blk * 128 + rem];
        }
    }
    __syncthreads();
    float2 v[8][4];
    #pragma unroll
    for (int f2 = 0; f2 < 8; ++f2) {
        #pragma unroll
        for (int k = 0; k < 4; ++k)
            v[f2][k] = ls[f2 * 256 + d3r * 32 + co4 * 4 + k];
    }
    const float sc = 1.f / 131072.f;
    #pragma unroll 2
    for (int i = 0; i < 16; ++i) {
        int d2 = d2q * 16 + i;
        float rx = 0.f, ry = 0.f, rz = 0.f, rw = 0.f;
        #pragma unroll
        for (int f2 = 0; f2 < 8; ++f2) {
            float2 e = tw[(f2 * d2) & 63];      // wave-uniform broadcast
            rx += v[f2][0].x * e.x - v[f2][0].y * e.y;
            ry += v[f2][1].x * e.x - v[f2][1].y * e.y;
            rz += v[f2][2].x * e.x - v[f2][2].y * e.y;
            rw += v[f2][3].x * e.x - v[f2][3].y * e.y;
        }
        vf4 r = {rx * sc, ry * sc, rz * sc, rw * sc};
        __builtin_nontemporal_store(r, (vf4*)(obase + d2 * 2048));
    }
}

extern "C" void kernel_launch(void* const* d_in, const int* in_sizes, int n_in,
                              void* d_out, int out_size, void* d_ws, size_t ws_size,
                              hipStream_t stream) {
    const float* x  = (const float*)d_in[0];
    const float* wr = (const float*)d_in[1];
    const float* wi = (const float*)d_in[2];
    float* out = (float*)d_out;

    float2* Weff = (float2*)d_ws;            // 8192 float2
    float2* T    = Weff + 8192;              // 8192 float2
    float2* S1   = T + 8192;                 // 524288 float2 (4 MiB)
    float2* S6   = S1 + 524288;              // 524288 float2 (4 MiB)

    k_weff  <<<256,  256,  0, stream>>>(wr, wi, Weff);
    k_T     <<<32,   1024, 0, stream>>>(Weff, T);
    k_dft2  <<<2048, 256,  0, stream>>>(x, S1);
    k_mid3  <<<256,  1024, 0, stream>>>(S1, T, S6);
    k_final2<<<2048, 256,  0, stream>>>(S6, out);
}

// Round 6
// 222.565 us; speedup vs baseline: 1.0842x; 1.0015x over previous
//
#include <hip/hip_runtime.h>

// SpectralConv3d — algebra (verified by passing runs r0-r3):
//   fftn axes (2,3,4) = (D2, D3, CIN); output zero for d1>=8
//   Weff[c,o,f3] = sum_ij w[c,o,i,j,f3];  DFT_c+mix+IDFT_c folds to T[c][f3][co]
//   ifftn norm 1/131072
//
// Round-6: r5 + ONE fix. r4/r5 failed because k_final3 staged only 512 of the
// 1024 float4 of the s5 slab (float4 = 2 float2; slab = 2048 float2), leaving
// ls5[f2>=4] as uninitialized LDS. Staging loop now covers all 1024 float4.
//   k_weff  : 256 wgs, ij-sum split 8-way + LDS reduce          [r3 verbatim]
//   k_T     : 32 wgs x 1024, split reductions                   [r3 verbatim]
//   k_dft2  : 2048 wgs (slab,d3): d2-DFT, x read EXACTLY once   [r3 verbatim]
//   k_mix   : 256 wgs x 1024 (slab,f2): d3-DFT + T-mix -> s5 (512 KB)
//   k_final3: 2048 wgs: s5 slab in LDS, d3-IDFT own 8 d3, d2-IDFT, NT stores

#define PI2F 6.28318530717958647692f

typedef float vf4 __attribute__((ext_vector_type(4)));  // native vec for NT stores

// Weff[fc][o][f3] = sum_{ij} (wr + i wi)[fc][o][i][j][f3]
// 256 wgs x 256 thr: wg owns 32 elems, ij split 8-way across thread groups.
__global__ void k_weff(const float* __restrict__ wr, const float* __restrict__ wi,
                       float2* __restrict__ Weff) {
    __shared__ float2 ls[256];
    int t = threadIdx.x;
    int eL = t & 31, ijg = t >> 5;
    int e = blockIdx.x * 32 + eL;                 // e = (fc*32+o)*8 + f3
    int base = (e >> 3) * 512 + (e & 7) + ijg * 64;   // ij stride 8 floats
    float sr = 0.f, si = 0.f;
    #pragma unroll
    for (int j = 0; j < 8; ++j) { sr += wr[base + j * 8]; si += wi[base + j * 8]; }
    ls[t] = make_float2(sr, si);
    __syncthreads();
    if (t < 32) {
        float2 a = ls[t];
        #pragma unroll
        for (int g = 1; g < 8; ++g) { float2 v = ls[g * 32 + t]; a.x += v.x; a.y += v.y; }
        Weff[blockIdx.x * 32 + t] = a;
    }
}

// T[c][f3][co] = sum_{fc,o} E32^-(fc c) Weff[fc][o][f3] E32^+(o co)
// 32 wgs (c) x 1024 thr; both 32-sums split 4-way.
__global__ void k_T(const float2* __restrict__ Weff, float2* __restrict__ T) {
    __shared__ float2 tw32[32];
    __shared__ float2 P[1024];
    __shared__ float2 A[256];
    int t = threadIdx.x;
    int c = blockIdx.x;
    if (t < 32) {
        float s, co_;
        __sincosf((PI2F / 32.f) * (float)t, &s, &co_);
        tw32[t] = make_float2(co_, s);
    }
    __syncthreads();
    {   // stage 1 partial: A[o][f3] = sum_fc Weff[fc][o*8+f3] * conj(tw32[fc*c])
        int g = t >> 8, rem = t & 255;            // rem = o*8+f3
        float2 acc = make_float2(0.f, 0.f);
        #pragma unroll
        for (int k = 0; k < 8; ++k) {
            int fc = g * 8 + k;
            float2 v = Weff[fc * 256 + rem];
            float2 e = tw32[(fc * c) & 31];
            acc.x += v.x * e.x + v.y * e.y;
            acc.y += v.y * e.x - v.x * e.y;
        }
        P[t] = acc;
    }
    __syncthreads();
    if (t < 256) {
        float2 a = P[t];
        #pragma unroll
        for (int g = 1; g < 4; ++g) { float2 v = P[g * 256 + t]; a.x += v.x; a.y += v.y; }
        A[t] = a;
    }
    __syncthreads();
    {   // stage 2 partial: T[c][f3][co] = sum_o A[o*8+f3] * tw32[o*co]
        int g = t >> 8, rem = t & 255;
        int f3 = rem >> 5, co = rem & 31;
        float2 acc = make_float2(0.f, 0.f);
        #pragma unroll
        for (int k = 0; k < 8; ++k) {
            int o = g * 8 + k;
            float2 v = A[o * 8 + f3];
            float2 e = tw32[(o * co) & 31];
            acc.x += v.x * e.x - v.y * e.y;
            acc.y += v.x * e.y + v.y * e.x;
        }
        P[t] = acc;
    }
    __syncthreads();
    if (t < 256) {
        float2 a = P[t];
        #pragma unroll
        for (int g = 1; g < 4; ++g) { float2 v = P[g * 256 + t]; a.x += v.x; a.y += v.y; }
        T[c * 256 + t] = a;
    }
}

// d2-DFT: S1[s][f2][d3][c] = sum_d2 x[b][d1][d2][d3][c] E64^-(f2 d2)
// 2048 wgs = (s=32) x (d3=64); 256 thr = (d2g=8) x (c=32); x read exactly once.
__global__ void k_dft2(const float* __restrict__ x, float2* __restrict__ S1) {
    __shared__ float2 tw64[64];
    __shared__ float2 P[2048];                    // [d2g*8+f2][c]  16 KB
    int t = threadIdx.x;
    int gid = blockIdx.x;
    int d3 = gid & 63, s = gid >> 6;
    int b = s >> 3, d1 = s & 7;
    int c = t & 31, d2g = t >> 5;
    if (t < 64) {
        float sn, cs;
        __sincosf((PI2F / 64.f) * (float)t, &sn, &cs);
        tw64[t] = make_float2(cs, sn);
    }
    __syncthreads();
    const float* xp = x + (size_t)b * 8388608 + (size_t)d1 * 131072 + d3 * 32 + c;
    float2 acc[8];
    #pragma unroll
    for (int f2 = 0; f2 < 8; ++f2) acc[f2] = make_float2(0.f, 0.f);
    #pragma unroll
    for (int k = 0; k < 8; ++k) {
        int d2 = d2g * 8 + k;
        float v = xp[d2 * 2048];
        #pragma unroll
        for (int f2 = 0; f2 < 8; ++f2) {
            float2 e = tw64[(f2 * d2) & 63];
            acc[f2].x += v * e.x;
            acc[f2].y -= v * e.y;
        }
    }
    #pragma unroll
    for (int f2 = 0; f2 < 8; ++f2) P[(d2g * 8 + f2) * 32 + c] = acc[f2];
    __syncthreads();
    {
        int f2 = t >> 5, cc = t & 31;
        float2 a = make_float2(0.f, 0.f);
        #pragma unroll
        for (int g = 0; g < 8; ++g) {
            float2 v = P[(g * 8 + f2) * 32 + cc];
            a.x += v.x; a.y += v.y;
        }
        S1[(size_t)(s * 8 + f2) * 2048 + d3 * 32 + cc] = a;
    }
}

// Mix: 256 wgs = (s,f2) x 1024 thr.
//   A: s2[f3][c]  = sum_d3 S1slab[d3][c] E64^-(f3 d3)   (split 4-way over d3)
//   B: s5[f3][co] = sum_c  s2 * T[c][f3][co]            (split 4-way over c)
// writes s5g[(s*8+f2)*256 + f3*32+co]  (512 KB total)
__global__ void k_mix(const float2* __restrict__ S1, const float2* __restrict__ T,
                      float2* __restrict__ s5g) {
    __shared__ float2 sl1[2048];   // [d3][c] 16 KB
    __shared__ float2 P[1024];
    __shared__ float2 s2[256];
    __shared__ float2 tw[64];
    int t = threadIdx.x;
    int gid = blockIdx.x;          // = s*8 + f2
    if (t < 64) {
        float sn, cs;
        __sincosf((PI2F / 64.f) * (float)t, &sn, &cs);
        tw[t] = make_float2(cs, sn);
    }
    {
        const float4* src = (const float4*)(S1 + (size_t)gid * 2048);
        ((float4*)sl1)[t] = src[t];
    }
    __syncthreads();
    {   // A partial
        int g = t >> 8, rem = t & 255;
        int f3 = rem >> 5, c = rem & 31;
        float2 a = make_float2(0.f, 0.f);
        #pragma unroll 4
        for (int k = 0; k < 16; ++k) {
            int d3 = g * 16 + k;
            float2 v = sl1[d3 * 32 + c];
            float2 e = tw[(f3 * d3) & 63];        // conj applied
            a.x += v.x * e.x + v.y * e.y;
            a.y += v.y * e.x - v.x * e.y;
        }
        P[t] = a;
    }
    __syncthreads();
    if (t < 256) {
        float2 a = P[t];
        #pragma unroll
        for (int g = 1; g < 4; ++g) { float2 v = P[g * 256 + t]; a.x += v.x; a.y += v.y; }
        s2[t] = a;
    }
    __syncthreads();
    {   // B partial
        int g = t >> 8, rem = t & 255;
        int f3 = rem >> 5, co = rem & 31;
        float2 a = make_float2(0.f, 0.f);
        #pragma unroll
        for (int k = 0; k < 8; ++k) {
            int cc = g * 8 + k;
            float2 v = s2[f3 * 32 + cc];
            float2 w = T[cc * 256 + f3 * 32 + co];
            a.x += v.x * w.x - v.y * w.y;
            a.y += v.x * w.y + v.y * w.x;
        }
        P[t] = a;
    }
    __syncthreads();
    if (t < 256) {
        float2 a = P[t];
        #pragma unroll
        for (int g = 1; g < 4; ++g) { float2 v = P[g * 256 + t]; a.x += v.x; a.y += v.y; }
        s5g[(size_t)gid * 256 + t] = a;
    }
}

// k_final3: gid = (b*64 + d1)*8 + blk   (2048 wgs)
//   d1>=8: pure nontemporal zero fill.
//   d1< 8: ls5[f2][f3][co] <- s5 slab (16 KB = 1024 float4); d3-IDFT for own
//          8 d3 -> sq6[f2][d3r][co]; regs fragment; d2-IDFT; NT float4 stores.
__global__ void k_final3(const float2* __restrict__ s5g, float* __restrict__ out) {
    __shared__ float2 ls5[2048];    // [f2][f3][co] 16 KB
    __shared__ float2 sq6[2048];    // [f2][d3r][co] 16 KB
    __shared__ float2 tw[64];
    int t = threadIdx.x;
    int gid = blockIdx.x;
    int blk = gid & 7;
    int d1  = (gid >> 3) & 63;
    int b   = gid >> 9;
    int co4 = t & 7;
    int d3r8 = (t >> 3) & 7;
    int d2q = t >> 6;               // wave-uniform
    float* obase = out + (size_t)b * 8388608 + (size_t)d1 * 131072
                 + (blk * 8 + d3r8) * 32 + co4 * 4;
    if (d1 >= 8) {
        vf4 z = {0.f, 0.f, 0.f, 0.f};
        #pragma unroll
        for (int i = 0; i < 16; ++i) {
            int d2 = d2q * 16 + i;
            __builtin_nontemporal_store(z, (vf4*)(obase + d2 * 2048));
        }
        return;
    }
    if (t < 64) {
        float sn, cs;
        __sincosf((PI2F / 64.f) * (float)t, &sn, &cs);
        tw[t] = make_float2(cs, sn);            // E^+
    }
    {   // stage s5 slab: 2048 float2 = 1024 float4 (r4/r5 bug: only did 512)
        const float4* src = (const float4*)(s5g + (size_t)(b * 8 + d1) * 2048);
        float4* dst = (float4*)ls5;
        #pragma unroll
        for (int j = 0; j < 4; ++j) dst[t + j * 256] = src[t + j * 256];
    }
    __syncthreads();
    {   // d3-IDFT for this wg's 8 d3 values
        int co = t & 31, d3r = t >> 5;
        int d3 = blk * 8 + d3r;
        #pragma unroll
        for (int f2 = 0; f2 < 8; ++f2) {
            float2 a = make_float2(0.f, 0.f);
            #pragma unroll
            for (int f3 = 0; f3 < 8; ++f3) {
                float2 v = ls5[f2 * 256 + f3 * 32 + co];
                float2 e = tw[(f3 * d3) & 63];    // E^+
                a.x += v.x * e.x - v.y * e.y;
                a.y += v.x * e.y + v.y * e.x;
            }
            sq6[f2 * 256 + d3r * 32 + co] = a;
        }
    }
    __syncthreads();
    float2 v[8][4];
    #pragma unroll
    for (int f2 = 0; f2 < 8; ++f2) {
        #pragma unroll
        for (int k = 0; k < 4; ++k)
            v[f2][k] = sq6[f2 * 256 + d3r8 * 32 + co4 * 4 + k];
    }
    const float sc = 1.f / 131072.f;
    #pragma unroll 2
    for (int i = 0; i < 16; ++i) {
        int d2 = d2q * 16 + i;
        float rx = 0.f, ry = 0.f, rz = 0.f, rw = 0.f;
        #pragma unroll
        for (int f2 = 0; f2 < 8; ++f2) {
            float2 e = tw[(f2 * d2) & 63];      // wave-uniform broadcast
            rx += v[f2][0].x * e.x - v[f2][0].y * e.y;
            ry += v[f2][1].x * e.x - v[f2][1].y * e.y;
            rz += v[f2][2].x * e.x - v[f2][2].y * e.y;
            rw += v[f2][3].x * e.x - v[f2][3].y * e.y;
        }
        vf4 r = {rx * sc, ry * sc, rz * sc, rw * sc};
        __builtin_nontemporal_store(r, (vf4*)(obase + d2 * 2048));
    }
}

extern "C" void kernel_launch(void* const* d_in, const int* in_sizes, int n_in,
                              void* d_out, int out_size, void* d_ws, size_t ws_size,
                              hipStream_t stream) {
    const float* x  = (const float*)d_in[0];
    const float* wr = (const float*)d_in[1];
    const float* wi = (const float*)d_in[2];
    float* out = (float*)d_out;

    float2* Weff = (float2*)d_ws;            // 8192 float2
    float2* T    = Weff + 8192;              // 8192 float2
    float2* S1   = T + 8192;                 // 524288 float2 (4 MiB)
    float2* s5g  = S1 + 524288;              // 65536 float2 (512 KiB)

    k_weff  <<<256,  256,  0, stream>>>(wr, wi, Weff);
    k_T     <<<32,   1024, 0, stream>>>(Weff, T);
    k_dft2  <<<2048, 256,  0, stream>>>(x, S1);
    k_mix   <<<256,  1024, 0, stream>>>(S1, T, s5g);
    k_final3<<<2048, 256,  0, stream>>>(s5g, out);
}